// Round 1
// baseline (1473.347 us; speedup 1.0000x reference)
//
#include <hip/hip_runtime.h>
#include <math.h>

// HeterogeneousGNN fused kernel for MI355X (gfx950).
// Strategy: one workgroup (512 thr = 8 waves) per batch element; H[b] lives in
// LDS (bf16, XOR-swizzled) across all 3 layers. Per layer, per half h in
// {pos, neg}: G = H @ W[l][h]^T (GEMM1, MFMA 16x16x32 bf16), stored transposed
// in LDS; then acc += Ac[h] @ G (GEMM2) with Ac = [sigmoid-masked A_pos, -A_neg]
// precomputed to bf16 in d_ws by a prep kernel. Epilogue: exact GELU + LN on
// register accumulators, write back H. Readout: mean over nodes + final LN.
// LDS: H 64 KB + G 64 KB = 128 KB (dynamic, needs hipFuncSetAttribute).

typedef float  f32x4  __attribute__((ext_vector_type(4)));
typedef short  s16x8  __attribute__((ext_vector_type(8)));
typedef __bf16 bf16x8 __attribute__((ext_vector_type(8)));

#define NNODE 256
#define DIMF  128

__device__ __forceinline__ unsigned short f2bf(float f) {
  unsigned int u = __builtin_bit_cast(unsigned int, f);
  u = (u + 0x7fffu + ((u >> 16) & 1u)) >> 16;   // round-to-nearest-even
  return (unsigned short)u;
}
__device__ __forceinline__ float bf2f(unsigned short h) {
  return __builtin_bit_cast(float, (unsigned int)h << 16);
}

// LDS byte addresses, XOR-swizzled (T2): spreads the 16-row-stride ds_read_b128
// column-slice pattern across bank groups (else 16-way conflict).
__device__ __forceinline__ int haddr(int v, int d) {          // H: [256][128] bf16
  return v * 256 + ((d * 2) ^ ((v & 7) << 4));
}
__device__ __forceinline__ int gaddr(int o, int v) {          // G^T: [128][256] bf16
  return 65536 + o * 512 + ((v * 2) ^ ((o & 7) << 4));
}

#define MFMA16(a, b, c) __builtin_amdgcn_mfma_f32_16x16x32_bf16( \
    __builtin_bit_cast(bf16x8, (a)), __builtin_bit_cast(bf16x8, (b)), (c), 0, 0, 0)

// ---- prep: sigmoid+mask adjacency -> bf16 (neg sign folded), W -> bf16 ----
__global__ void prep_kernel(const float* __restrict__ alp, const float* __restrict__ aln,
                            const float* __restrict__ wp,  const float* __restrict__ wn,
                            unsigned short* __restrict__ A2, unsigned short* __restrict__ W2) {
  int idx = blockIdx.x * 512 + threadIdx.x;            // 163840 threads total
  if (idx < 65536) {
    float ap = 1.f / (1.f + expf(-alp[idx]));
    float an = 1.f / (1.f + expf(-aln[idx]));
    bool  m  = ap > an;
    A2[idx]          = f2bf(m ? ap : 0.f);
    A2[65536 + idx]  = f2bf(m ? 0.f : -an);            // sign folded: GEMM2 always adds
  } else {
    int j = idx - 65536;                               // 0 .. 98303
    int l = j >> 15;                                   // layer (2*16384 per layer)
    int h = (j >> 14) & 1;
    int e = j & 16383;
    const float* src = h ? wn : wp;
    W2[j] = f2bf(src[l * 16384 + e]);
  }
}

__global__ __launch_bounds__(512, 2) void gnn_kernel(
    const float* __restrict__ X,
    const unsigned short* __restrict__ A2,
    const unsigned short* __restrict__ W2,
    const float* __restrict__ ln_g, const float* __restrict__ ln_b,
    const float* __restrict__ ro_g, const float* __restrict__ ro_b,
    float* __restrict__ out) {
  extern __shared__ char smem[];
  const int tid  = threadIdx.x;
  const int wid  = tid >> 6;
  const int lane = tid & 63;
  const int g    = lane >> 4;       // k-group 0..3
  const int r16  = lane & 15;
  const int b    = blockIdx.x;

  // ---- stage H = bf16(X[b]) into LDS (swizzled) ----
  {
    const float4* Xb = (const float4*)(X + (size_t)b * NNODE * DIMF);
#pragma unroll
    for (int i = 0; i < 16; ++i) {
      int idx = tid + i * 512;                // 8192 float4 chunks
      int v   = idx >> 5;
      int d   = (idx & 31) * 4;
      float4 f = Xb[idx];
      ushort4 p;
      p.x = f2bf(f.x); p.y = f2bf(f.y); p.z = f2bf(f.z); p.w = f2bf(f.w);
      *(ushort4*)(smem + haddr(v, d)) = p;
    }
  }
  __syncthreads();

  f32x4 acc[2][8];                             // GEMM2 accumulator: 32 rows x 128 cols / wave
  const f32x4 fzero = {0.f, 0.f, 0.f, 0.f};

  for (int l = 0; l < 3; ++l) {
#pragma unroll
    for (int rt = 0; rt < 2; ++rt)
#pragma unroll
      for (int ct = 0; ct < 8; ++ct) acc[rt][ct] = fzero;

    for (int h = 0; h < 2; ++h) {
      // ---- GEMM1: G[v,o] = sum_d H[v,d] * W[o,d]; wave tile 64x64 (4x4 MFMA tiles) ----
      const int vblk = (wid >> 1) * 64;
      const int oblk = (wid & 1) * 64;
      const unsigned short* Wl = W2 + (l * 2 + h) * DIMF * DIMF;
      f32x4 gacc[4][4];
#pragma unroll
      for (int mt = 0; mt < 4; ++mt)
#pragma unroll
        for (int nt = 0; nt < 4; ++nt) gacc[mt][nt] = fzero;

#pragma unroll
      for (int k0 = 0; k0 < DIMF; k0 += 32) {
        s16x8 af[4], bfr[4];
#pragma unroll
        for (int mt = 0; mt < 4; ++mt)
          af[mt] = *(const s16x8*)(smem + haddr(vblk + mt * 16 + r16, k0 + g * 8));
#pragma unroll
        for (int nt = 0; nt < 4; ++nt)
          bfr[nt] = *(const s16x8*)(Wl + (oblk + nt * 16 + r16) * DIMF + k0 + g * 8);
#pragma unroll
        for (int mt = 0; mt < 4; ++mt)
#pragma unroll
          for (int nt = 0; nt < 4; ++nt)
            gacc[mt][nt] = MFMA16(af[mt], bfr[nt], gacc[mt][nt]);
      }
      __syncthreads();   // prior GEMM2 reads of G are done before overwriting
      // store G transposed: GT[o][v], packing 4 consecutive v per lane (ds_write_b64)
#pragma unroll
      for (int mt = 0; mt < 4; ++mt)
#pragma unroll
        for (int nt = 0; nt < 4; ++nt) {
          int o  = oblk + nt * 16 + r16;       // C/D: col = lane&15
          int v0 = vblk + mt * 16 + g * 4;     // C/D: row = (lane>>4)*4 + reg
          ushort4 p;
          p.x = f2bf(gacc[mt][nt][0]);
          p.y = f2bf(gacc[mt][nt][1]);
          p.z = f2bf(gacc[mt][nt][2]);
          p.w = f2bf(gacc[mt][nt][3]);
          *(ushort4*)(smem + gaddr(o, v0)) = p;
        }
      __syncthreads();

      // ---- GEMM2: acc += Ac[h] @ G; wave tile 32 rows x 128 cols (2x8 tiles) ----
      const unsigned short* Ah = A2 + h * NNODE * NNODE;
#pragma unroll
      for (int k0 = 0; k0 < NNODE; k0 += 32) {
        s16x8 af[2], bfr[8];
#pragma unroll
        for (int rt = 0; rt < 2; ++rt)
          af[rt] = *(const s16x8*)(Ah + (wid * 32 + rt * 16 + r16) * NNODE + k0 + g * 8);
#pragma unroll
        for (int ct = 0; ct < 8; ++ct)
          bfr[ct] = *(const s16x8*)(smem + gaddr(ct * 16 + r16, k0 + g * 8));
#pragma unroll
        for (int rt = 0; rt < 2; ++rt)
#pragma unroll
          for (int ct = 0; ct < 8; ++ct)
            acc[rt][ct] = MFMA16(af[rt], bfr[ct], acc[rt][ct]);
      }
      __syncthreads();   // G fully consumed before next half overwrites it
    }

    // ---- epilogue: exact GELU + LayerNorm -> H (bf16) ----
    float lg[8], lb[8];
#pragma unroll
    for (int ct = 0; ct < 8; ++ct) {
      lg[ct] = ln_g[l * DIMF + ct * 16 + r16];
      lb[ct] = ln_b[l * DIMF + ct * 16 + r16];
    }
#pragma unroll
    for (int rt = 0; rt < 2; ++rt)
#pragma unroll
      for (int ct = 0; ct < 8; ++ct)
#pragma unroll
        for (int r = 0; r < 4; ++r) {
          float x = acc[rt][ct][r];
          acc[rt][ct][r] = 0.5f * x * (1.f + erff(x * 0.70710678f));
        }
#pragma unroll
    for (int rt = 0; rt < 2; ++rt)
#pragma unroll
      for (int r = 0; r < 4; ++r) {
        float s1 = 0.f, s2 = 0.f;
#pragma unroll
        for (int ct = 0; ct < 8; ++ct) {
          float v = acc[rt][ct][r];
          s1 += v; s2 += v * v;
        }
#pragma unroll
        for (int m = 1; m < 16; m <<= 1) {   // 16-lane row-group reduce
          s1 += __shfl_xor(s1, m);
          s2 += __shfl_xor(s2, m);
        }
        float mu  = s1 * (1.f / 128.f);
        float var = s2 * (1.f / 128.f) - mu * mu;
        float rs  = rsqrtf(var + 1e-5f);
        int row = wid * 32 + rt * 16 + g * 4 + r;
#pragma unroll
        for (int ct = 0; ct < 8; ++ct) {
          float y = (acc[rt][ct][r] - mu) * rs * lg[ct] + lb[ct];
          *(unsigned short*)(smem + haddr(row, ct * 16 + r16)) = f2bf(y);
        }
      }
    __syncthreads();
  }

  // ---- readout: mean over nodes + final LN ----
  {
    int d   = tid & 127;
    int grp = tid >> 7;
    float s = 0.f;
    for (int v = grp * 64; v < grp * 64 + 64; ++v)
      s += bf2f(*(const unsigned short*)(smem + haddr(v, d)));
    float* red = (float*)(smem + 65536);     // G region is dead now
    red[grp * 128 + d] = s;
    __syncthreads();
    if (tid < 128) {
      float hv = (red[tid] + red[128 + tid] + red[256 + tid] + red[384 + tid]) * (1.f / 256.f);
      red[512 + tid] = hv;
    }
    __syncthreads();
    if (tid < 64) {
      float a  = red[512 + tid];
      float b2 = red[512 + 64 + tid];
      float s1 = a + b2, s2 = a * a + b2 * b2;
#pragma unroll
      for (int m = 1; m < 64; m <<= 1) {
        s1 += __shfl_xor(s1, m);
        s2 += __shfl_xor(s2, m);
      }
      float mu  = s1 * (1.f / 128.f);
      float var = s2 * (1.f / 128.f) - mu * mu;
      float rs  = rsqrtf(var + 1e-5f);
      out[(size_t)b * 128 + tid]      = (a  - mu) * rs * ro_g[tid]      + ro_b[tid];
      out[(size_t)b * 128 + 64 + tid] = (b2 - mu) * rs * ro_g[64 + tid] + ro_b[64 + tid];
    }
  }
}

extern "C" void kernel_launch(void* const* d_in, const int* in_sizes, int n_in,
                              void* d_out, int out_size, void* d_ws, size_t ws_size,
                              hipStream_t stream) {
  const float* X   = (const float*)d_in[0];
  const float* alp = (const float*)d_in[1];
  const float* aln = (const float*)d_in[2];
  const float* wp  = (const float*)d_in[3];
  const float* wn  = (const float*)d_in[4];
  const float* lng = (const float*)d_in[5];
  const float* lnb = (const float*)d_in[6];
  const float* rog = (const float*)d_in[7];
  const float* rob = (const float*)d_in[8];
  float* out = (float*)d_out;

  // d_ws layout: A2 (2*65536 bf16 = 256 KB) | W2 (6*16384 bf16 = 192 KB); ~448 KB total.
  unsigned short* A2 = (unsigned short*)d_ws;
  unsigned short* W2 = A2 + 2 * 65536;

  (void)hipFuncSetAttribute(reinterpret_cast<const void*>(gnn_kernel),
                            hipFuncAttributeMaxDynamicSharedMemorySize, 131072);

  prep_kernel<<<320, 512, 0, stream>>>(alp, aln, wp, wn, A2, W2);
  gnn_kernel<<<2048, 512, 131072, stream>>>(X, A2, W2, lng, lnb, rog, rob, out);
}